// Round 1
// baseline (2002.529 us; speedup 1.0000x reference)
//
#include <hip/hip_runtime.h>

// Problem constants (fixed by the reference):
//   N = E = 300000, H = 768, B = 256, A = 3129
#define HB    768
#define BATCH 256
#define LDG   2304   // lang_g row stride (3*H)

// ---------------------------------------------------------------------------
// Segment sum over sorted segment ids.
// Grid: nBlocks x 192 threads. Each thread owns 4 contiguous columns (float4),
// a block streams a contiguous chunk of rows, accumulating in registers and
// flushing with atomicAdd only when the segment id changes (sorted input =>
// ~1-3 flushes per block).
// out has row stride LDG (writes into a column slice of lang_g).
// ---------------------------------------------------------------------------
__global__ __launch_bounds__(192) void segsum_kernel(
    const float* __restrict__ feat, const int* __restrict__ seg,
    float* __restrict__ out, int N, int rowsPerBlock)
{
    const int r0 = blockIdx.x * rowsPerBlock;
    if (r0 >= N) return;
    const int r1 = min(r0 + rowsPerBlock, N);
    const int col = threadIdx.x * 4;

    float4 acc = make_float4(0.f, 0.f, 0.f, 0.f);
    int cur = seg[r0];

    for (int r = r0; r < r1; ++r) {
        const int s = seg[r];
        if (s != cur) {
            float* o = out + (long)cur * LDG + col;
            atomicAdd(o + 0, acc.x);
            atomicAdd(o + 1, acc.y);
            atomicAdd(o + 2, acc.z);
            atomicAdd(o + 3, acc.w);
            acc = make_float4(0.f, 0.f, 0.f, 0.f);
            cur = s;
        }
        const float4 v = *(const float4*)(feat + (long)r * HB + col);
        acc.x += v.x; acc.y += v.y; acc.z += v.z; acc.w += v.w;
    }
    float* o = out + (long)cur * LDG + col;
    atomicAdd(o + 0, acc.x);
    atomicAdd(o + 1, acc.y);
    atomicAdd(o + 2, acc.z);
    atomicAdd(o + 3, acc.w);
}

// ---------------------------------------------------------------------------
// fp32 GEMM with fused bias (+optional ReLU):  C[M,N] = act(A[M,K] @ W[K,N] + b)
// A row-major stride lda, W row-major stride N, C row-major stride ldc.
// Tile 64x64, BK=16, 256 threads, 4x4 micro-tile per thread.
// NVEC=false handles N not divisible by 4 / unaligned W rows (scalar, guarded).
// M is assumed a multiple of 64 (M=256 here).
// ---------------------------------------------------------------------------
template<bool RELU, bool NVEC>
__global__ __launch_bounds__(256) void gemm_bias(
    const float* __restrict__ A, const float* __restrict__ W,
    const float* __restrict__ bias, float* __restrict__ C,
    int N, int K, int lda, int ldc)
{
    constexpr int BM = 64, BN = 64, BK = 16;
    __shared__ float As[BK][BM + 4];
    __shared__ float Ws[BK][BN + 4];

    const int tid = threadIdx.x;
    const int bm  = blockIdx.y * BM;
    const int bn  = blockIdx.x * BN;
    const int tx  = tid & 15;        // n micro index
    const int ty  = tid >> 4;        // m micro index
    const int a_row = tid >> 2;      // 0..63
    const int a_col = (tid & 3) << 2;
    const int w_row = tid >> 4;      // 0..15
    const int w_col = (tid & 15) << 2;

    float acc[4][4] = {};

    const float* Aptr = A + (long)(bm + a_row) * lda + a_col;

    for (int k0 = 0; k0 < K; k0 += BK) {
        // stage A tile (transposed into LDS: As[k][m])
        const float4 av = *(const float4*)(Aptr + k0);
        As[a_col + 0][a_row] = av.x;
        As[a_col + 1][a_row] = av.y;
        As[a_col + 2][a_row] = av.z;
        As[a_col + 3][a_row] = av.w;

        // stage W tile
        const int   n0 = bn + w_col;
        const float* Wp = W + (long)(k0 + w_row) * N + n0;
        float4 wv;
        if (NVEC) {
            wv = *(const float4*)Wp;
        } else {
            wv.x = (n0 + 0 < N) ? Wp[0] : 0.f;
            wv.y = (n0 + 1 < N) ? Wp[1] : 0.f;
            wv.z = (n0 + 2 < N) ? Wp[2] : 0.f;
            wv.w = (n0 + 3 < N) ? Wp[3] : 0.f;
        }
        *(float4*)&Ws[w_row][w_col] = wv;

        __syncthreads();

#pragma unroll
        for (int kk = 0; kk < BK; ++kk) {
            const float4 a4 = *(const float4*)&As[kk][ty << 2];
            const float4 b4 = *(const float4*)&Ws[kk][tx << 2];
            const float a[4] = {a4.x, a4.y, a4.z, a4.w};
            const float b[4] = {b4.x, b4.y, b4.z, b4.w};
#pragma unroll
            for (int i = 0; i < 4; ++i)
#pragma unroll
                for (int j = 0; j < 4; ++j)
                    acc[i][j] += a[i] * b[j];
        }
        __syncthreads();
    }

    // epilogue: bias (+ReLU), store
#pragma unroll
    for (int i = 0; i < 4; ++i) {
        const int m = bm + (ty << 2) + i;
        const int n = bn + (tx << 2);
        if (NVEC) {
            const float4 bv = *(const float4*)(bias + n);
            float4 o;
            o.x = acc[i][0] + bv.x;
            o.y = acc[i][1] + bv.y;
            o.z = acc[i][2] + bv.z;
            o.w = acc[i][3] + bv.w;
            if (RELU) {
                o.x = fmaxf(o.x, 0.f); o.y = fmaxf(o.y, 0.f);
                o.z = fmaxf(o.z, 0.f); o.w = fmaxf(o.w, 0.f);
            }
            *(float4*)(C + (long)m * ldc + n) = o;
        } else {
#pragma unroll
            for (int j = 0; j < 4; ++j) {
                if (n + j < N) {
                    float v = acc[i][j] + bias[n + j];
                    if (RELU) v = fmaxf(v, 0.f);
                    C[(long)m * ldc + n + j] = v;
                }
            }
        }
    }
}

extern "C" void kernel_launch(void* const* d_in, const int* in_sizes, int n_in,
                              void* d_out, int out_size, void* d_ws, size_t ws_size,
                              hipStream_t stream)
{
    const float* node_feat = (const float*)d_in[0];
    const float* edge_feat = (const float*)d_in[1];
    const float* q         = (const float*)d_in[2];
    const int*   node_seg  = (const int*)d_in[3];
    const int*   edge_seg  = (const int*)d_in[4];
    const float* W_lang    = (const float*)d_in[5];
    const float* b_lang    = (const float*)d_in[6];
    const float* W_mid     = (const float*)d_in[7];
    const float* b_mid     = (const float*)d_in[8];
    const float* W_mid2    = (const float*)d_in[9];
    const float* b_mid2    = (const float*)d_in[10];
    const float* W_ans     = (const float*)d_in[11];
    const float* b_ans     = (const float*)d_in[12];
    float* out = (float*)d_out;

    const int N = in_sizes[3];   // 300000 node rows
    const int E = in_sizes[4];   // 300000 edge rows
    const int A = 3129;

    // workspace layout (floats)
    float* lang_g = (float*)d_ws;                  // [256, 2304]
    float* mid    = lang_g + (size_t)BATCH * LDG;  // [256, 768]
    float* mid2   = mid    + (size_t)BATCH * HB;   // [256, 768]

    // zero the pooling accumulators (lang slice gets overwritten by GEMM)
    hipMemsetAsync(lang_g, 0, (size_t)BATCH * LDG * sizeof(float), stream);

    // segment sums -> lang_g[:, 0:768] and lang_g[:, 768:1536]
    const int nBlocks = 2048;
    const int rpbN = (N + nBlocks - 1) / nBlocks;
    const int rpbE = (E + nBlocks - 1) / nBlocks;
    segsum_kernel<<<nBlocks, 192, 0, stream>>>(node_feat, node_seg, lang_g, N, rpbN);
    segsum_kernel<<<nBlocks, 192, 0, stream>>>(edge_feat, edge_seg, lang_g + HB, E, rpbE);

    // lang = q @ W_lang + b_lang  -> lang_g[:, 1536:2304]
    gemm_bias<false, true><<<dim3(HB / 64, BATCH / 64), 256, 0, stream>>>(
        q, W_lang, b_lang, lang_g + 2 * HB, HB, HB, HB, LDG);

    // mid = relu(lang_g @ W_mid + b_mid)
    gemm_bias<true, true><<<dim3(HB / 64, BATCH / 64), 256, 0, stream>>>(
        lang_g, W_mid, b_mid, mid, HB, 3 * HB, LDG, HB);

    // mid2 = relu(mid @ W_mid2 + b_mid2)
    gemm_bias<true, true><<<dim3(HB / 64, BATCH / 64), 256, 0, stream>>>(
        mid, W_mid2, b_mid2, mid2, HB, HB, HB, HB);

    // pred = mid2 @ W_ans + b_ans  (N=3129: scalar-guarded W/stores)
    gemm_bias<false, false><<<dim3((A + 63) / 64, BATCH / 64), 256, 0, stream>>>(
        mid2, W_ans, b_ans, out, A, HB, HB, A);
}